// Round 1
// baseline (189.814 us; speedup 1.0000x reference)
//
#include <hip/hip_runtime.h>
#include <math.h>

#define B_N  4096
#define HALF 2048
#define D_K  128
#define TILE 64
#define NT   (B_N / TILE)   // 64 tiles per dim

// ---------------------------------------------------------------------------
// Shared tile machinery. K1 (min pass) and K2 (sum pass) MUST compute sim
// bit-identically, so both use these exact inlined functions (fixed fmaf
// chain order; no reassociation happens without -ffast-math).
// ---------------------------------------------------------------------------

// Load a 64-row x 128-col fp32 tile into LDS as float4 chunks with XOR
// swizzle (chunk' = chunk ^ (row & 7)) so the compute-phase reads are
// conflict-free (A) / 2-way (B, free).
__device__ __forceinline__ void load_tile(const float* __restrict__ src,
                                          int row0, float4* lds4) {
    int t = threadIdx.x;  // 0..255
#pragma unroll
    for (int it = 0; it < 8; ++it) {
        int f = t + 256 * it;          // float4 index within tile, 0..2047
        int r = f >> 5;                // row 0..63   (32 float4 per row)
        int c = f & 31;                // chunk 0..31
        float4 v = *(const float4*)(src + (size_t)(row0 + r) * D_K + c * 4);
        lds4[r * 32 + (c ^ (r & 7))] = v;
    }
}

// Each thread (ty = tid>>4, tx = tid&15) computes a 4x4 micro-tile at
// rows {ty+16m}, cols {tx+16n}. Deterministic fmaf chain, k ascending.
__device__ __forceinline__ void tile_mm(const float4* __restrict__ Al4,
                                        const float4* __restrict__ Bl4,
                                        int ty, int tx, float acc[4][4]) {
#pragma unroll
    for (int m = 0; m < 4; ++m)
#pragma unroll
        for (int n = 0; n < 4; ++n) acc[m][n] = 0.f;

#pragma unroll 8
    for (int c = 0; c < 32; ++c) {
        float4 a[4], b[4];
#pragma unroll
        for (int m = 0; m < 4; ++m) {
            int r = ty + 16 * m;
            a[m] = Al4[r * 32 + (c ^ (r & 7))];
        }
#pragma unroll
        for (int n = 0; n < 4; ++n) {
            int r = tx + 16 * n;
            b[n] = Bl4[r * 32 + (c ^ (r & 7))];
        }
#pragma unroll
        for (int m = 0; m < 4; ++m)
#pragma unroll
            for (int n = 0; n < 4; ++n) {
                float s = acc[m][n];
                s = fmaf(a[m].x, b[n].x, s);
                s = fmaf(a[m].y, b[n].y, s);
                s = fmaf(a[m].z, b[n].z, s);
                s = fmaf(a[m].w, b[n].w, s);
                acc[m][n] = s;
            }
    }
}

// ---------------------------------------------------------------------------
// K0: pos_sim / conf per row, zero the row accumulators, init the global min
//     to 3.0 (the value diff_sim takes on all excluded positions).
// ---------------------------------------------------------------------------
__global__ void k0_prep(const float* __restrict__ emb,
                        float* __restrict__ pos_sim,
                        float* __restrict__ conf,
                        float* __restrict__ pos_acc,
                        float* __restrict__ neg_acc,
                        unsigned* __restrict__ minbits) {
    int i = blockIdx.x * blockDim.x + threadIdx.x;
    if (i >= B_N) return;
    int p = (i + HALF) & (B_N - 1);
    const float4* a = (const float4*)(emb + (size_t)i * D_K);
    const float4* b = (const float4*)(emb + (size_t)p * D_K);
    float acc = 0.f;
#pragma unroll
    for (int k = 0; k < D_K / 4; ++k) {
        float4 av = a[k], bv = b[k];
        acc = fmaf(av.x, bv.x, acc);
        acc = fmaf(av.y, bv.y, acc);
        acc = fmaf(av.z, bv.z, acc);
        acc = fmaf(av.w, bv.w, acc);
    }
    float ps = expf(acc * 2.0f);                 // exp(raw / T), T = 0.5
    pos_sim[i] = ps;
    conf[i]    = (logf(ps) * 0.5f >= 0.8f) ? 1.0f : 0.0f;
    pos_acc[i] = 0.f;
    neg_acc[i] = 0.f;
    if (i == 0) *minbits = __float_as_uint(3.0f);
}

// ---------------------------------------------------------------------------
// K1: global min of diff_sim over the valid upper triangle.
//     diffs are >= 0, so uint-bit atomicMin == float min.
// ---------------------------------------------------------------------------
__global__ __launch_bounds__(256) void k1_min(const float* __restrict__ emb,
                                              const float* __restrict__ pos_sim,
                                              unsigned* __restrict__ minbits) {
    int bi = blockIdx.y, bj = blockIdx.x;
    if (bj < bi) return;  // lower-triangle tiles contribute only 3.0 (covered by init)

    __shared__ float4 Al4[TILE * 32];
    __shared__ float4 Bl4[TILE * 32];
    load_tile(emb, bi * TILE, Al4);
    load_tile(emb, bj * TILE, Bl4);
    __syncthreads();

    int ty = threadIdx.x >> 4, tx = threadIdx.x & 15;
    float acc[4][4];
    tile_mm(Al4, Bl4, ty, tx, acc);

    float lmin = 3.0f;
#pragma unroll
    for (int m = 0; m < 4; ++m) {
        int i = bi * TILE + ty + 16 * m;
        float psi = pos_sim[i];
#pragma unroll
        for (int n = 0; n < 4; ++n) {
            int j = bj * TILE + tx + 16 * n;
            // upper & ~excl:  j >= i, j != i, not (i<half && j==i+half)
            if (j > i && !(i < HALF && j == i + HALF)) {
                float sim = expf(acc[m][n] * 2.0f);
                lmin = fminf(lmin, fabsf(sim - psi));
            }
        }
    }
    // wave-level min reduce (64 lanes)
#pragma unroll
    for (int off = 32; off; off >>= 1)
        lmin = fminf(lmin, __shfl_xor(lmin, off));

    __shared__ float wmin[4];
    int lane = threadIdx.x & 63, wv = threadIdx.x >> 6;
    if (lane == 0) wmin[wv] = lmin;
    __syncthreads();
    if (threadIdx.x == 0) {
        float bm = fminf(fminf(wmin[0], wmin[1]), fminf(wmin[2], wmin[3]));
        atomicMin(minbits, __float_as_uint(bm));
    }
}

// ---------------------------------------------------------------------------
// K2: per-row sums of new_pos / new_neg over the full matrix, using the exact
//     per-element reference formula (handles all degenerate cases).
// ---------------------------------------------------------------------------
__global__ __launch_bounds__(256) void k2_sum(const float* __restrict__ emb,
                                              const float* __restrict__ pos_sim,
                                              const float* __restrict__ conf,
                                              const unsigned* __restrict__ minbits,
                                              float* __restrict__ pos_acc,
                                              float* __restrict__ neg_acc) {
    int bi = blockIdx.y, bj = blockIdx.x;

    __shared__ float4 Al4[TILE * 32];
    __shared__ float4 Bl4[TILE * 32];
    load_tile(emb, bi * TILE, Al4);
    load_tile(emb, bj * TILE, Bl4);
    __syncthreads();

    int ty = threadIdx.x >> 4, tx = threadIdx.x & 15;
    float acc[4][4];
    tile_mm(Al4, Bl4, ty, tx, acc);

    float minv = __uint_as_float(*minbits);

    float prow[4] = {0.f, 0.f, 0.f, 0.f};
    float nrow[4] = {0.f, 0.f, 0.f, 0.f};
#pragma unroll
    for (int m = 0; m < 4; ++m) {
        int i = bi * TILE + ty + 16 * m;
        float psi = pos_sim[i];
        bool ci = (conf[i] != 0.f);
        int pidx = (i + HALF) & (B_N - 1);
#pragma unroll
        for (int n = 0; n < 4; ++n) {
            int j = bj * TILE + tx + 16 * n;
            float sim = expf(acc[m][n] * 2.0f);
            bool is_pos = (j == pidx);
            float all_pos = is_pos ? sim : 0.f;
            float all_neg = (!is_pos && j != i) ? sim : 0.f;
            float d = (j > i && !(i < HALF && j == i + HALF))
                          ? fabsf(sim - psi) : 3.0f;
            bool sel = (d == minv) && ci;
            float np = (sel && all_pos == 0.f) ? 0.5f * all_neg : all_pos;
            float nn = (sel && all_neg != 0.f) ? 0.5f * all_neg : all_neg;
            prow[m] += np;
            nrow[m] += nn;
        }
    }
    // reduce across the 16 lanes (tx) that share each row
#pragma unroll
    for (int off = 1; off < 16; off <<= 1) {
#pragma unroll
        for (int m = 0; m < 4; ++m) {
            prow[m] += __shfl_xor(prow[m], off);
            nrow[m] += __shfl_xor(nrow[m], off);
        }
    }
    if (tx == 0) {
#pragma unroll
        for (int m = 0; m < 4; ++m) {
            int i = bi * TILE + ty + 16 * m;
            atomicAdd(&pos_acc[i], prow[m]);
            atomicAdd(&neg_acc[i], nrow[m]);
        }
    }
}

// ---------------------------------------------------------------------------
// K3: loss = -mean(log(pos / (pos + neg)))
// ---------------------------------------------------------------------------
__global__ void k3_loss(const float* __restrict__ pos_acc,
                        const float* __restrict__ neg_acc,
                        float* __restrict__ out) {
    int t = threadIdx.x;
    float s = 0.f;
    for (int i = t; i < B_N; i += 256) {
        float p = pos_acc[i], q = neg_acc[i];
        s += logf(p / (p + q));
    }
#pragma unroll
    for (int off = 32; off; off >>= 1) s += __shfl_xor(s, off);
    __shared__ float red[4];
    if ((t & 63) == 0) red[t >> 6] = s;
    __syncthreads();
    if (t == 0) {
        float tot = red[0] + red[1] + red[2] + red[3];
        *out = -tot / (float)B_N;
    }
}

// ---------------------------------------------------------------------------
extern "C" void kernel_launch(void* const* d_in, const int* in_sizes, int n_in,
                              void* d_out, int out_size, void* d_ws, size_t ws_size,
                              hipStream_t stream) {
    const float* emb = (const float*)d_in[0];
    float* out = (float*)d_out;

    float*    ws       = (float*)d_ws;
    float*    pos_sim  = ws;
    float*    conf     = ws + B_N;
    float*    pos_acc  = ws + 2 * B_N;
    float*    neg_acc  = ws + 3 * B_N;
    unsigned* minbits  = (unsigned*)(ws + 4 * B_N);

    k0_prep<<<B_N / 256, 256, 0, stream>>>(emb, pos_sim, conf, pos_acc, neg_acc, minbits);

    dim3 grid(NT, NT);
    k1_min<<<grid, 256, 0, stream>>>(emb, pos_sim, minbits);
    k2_sum<<<grid, 256, 0, stream>>>(emb, pos_sim, conf, minbits, pos_acc, neg_acc);
    k3_loss<<<1, 256, 0, stream>>>(pos_acc, neg_acc, out);
}

// Round 2
// 67.770 us; speedup vs baseline: 2.8009x; 2.8009x over previous
//
#include <hip/hip_runtime.h>
#include <math.h>

#define B_N  4096
#define HALF 2048
#define D_K  128
#define BT   128
#define NBT  (B_N / BT)   // 32 tiles per dim

typedef __attribute__((ext_vector_type(8))) short bf16x8;
typedef __attribute__((ext_vector_type(4))) float f32x4;

// exp(raw / T), T = 0.5. Fixed instruction sequence -> bit-identical in K1/K2.
__device__ __forceinline__ float sim_of(float rawdot) {
    return __expf(rawdot * 2.0f);
}

// fp32 -> bf16 round-to-nearest-even (no NaN in this data)
__device__ __forceinline__ ushort f2bf(float x) {
    unsigned u = __float_as_uint(x);
    unsigned r = u + 0x7FFFu + ((u >> 16) & 1u);
    return (ushort)(r >> 16);
}

// ---------------------------------------------------------------------------
// Stage a 128-row x 128-k bf16 tile into LDS with XOR swizzle on the 16B slot
// (byte ^= (row&7)<<4) so fragment ds_read_b128 is conflict-free (G4).
// Tile source region is contiguous (row-major, 256B/row).
// ---------------------------------------------------------------------------
__device__ __forceinline__ void stage_tile(const ushort* __restrict__ embh,
                                           int row0, ushort* lds) {
    int t = threadIdx.x;
    const float4* src = (const float4*)(embh + (size_t)row0 * D_K);
    char* dst = (char*)lds;
#pragma unroll
    for (int it = 0; it < 8; ++it) {
        int f = t + 256 * it;        // 16B chunk index, 0..2047
        int r = f >> 4;              // row 0..127 (16 chunks per 256B row)
        int c = f & 15;
        float4 v = src[f];
        int byte = (r << 8) | (((c ^ (r & 7)) & 15) << 4);
        *(float4*)(dst + byte) = v;
    }
}

__device__ __forceinline__ bf16x8 read_frag(const ushort* lds, int row, int kbyte) {
    int byte = ((row << 8) | kbyte) ^ ((row & 7) << 4);
    return *(const bf16x8*)((const char*)lds + byte);
}

// Each wave (wr,wc) computes a 64x64 sub-tile as 4x4 fragments of 16x16,
// K=128 in 4 steps of 32. A-frag: row = lane&15, k = (lane>>4)*8 + 0..7.
// B operand is emb^T, i.e. frag loads emb row (col index) identically.
__device__ __forceinline__ void tile_mfma(const ushort* Al, const ushort* Bl,
                                          int lane, int wr, int wc,
                                          f32x4 acc[4][4]) {
#pragma unroll
    for (int m = 0; m < 4; ++m)
#pragma unroll
        for (int n = 0; n < 4; ++n) acc[m][n] = (f32x4){0.f, 0.f, 0.f, 0.f};

    int rA = wr * 64 + (lane & 15);
    int rB = wc * 64 + (lane & 15);
    int kb0 = (lane >> 4) << 4;      // byte offset of this lane's 8 k's
#pragma unroll
    for (int ks = 0; ks < 4; ++ks) {
        int kb = ks * 64 + kb0;
        bf16x8 a[4], b[4];
#pragma unroll
        for (int m = 0; m < 4; ++m) a[m] = read_frag(Al, rA + m * 16, kb);
#pragma unroll
        for (int n = 0; n < 4; ++n) b[n] = read_frag(Bl, rB + n * 16, kb);
#pragma unroll
        for (int m = 0; m < 4; ++m)
#pragma unroll
            for (int n = 0; n < 4; ++n)
                acc[m][n] = __builtin_amdgcn_mfma_f32_16x16x32_bf16(
                    a[m], b[n], acc[m][n], 0, 0, 0);
    }
}

// ---------------------------------------------------------------------------
// K_cvt: fp32 -> bf16 copy of the embedding (done once per call; both passes
// read this so sim is computed from identical inputs).
// ---------------------------------------------------------------------------
__global__ __launch_bounds__(256) void k_convert(const float* __restrict__ emb,
                                                 ushort* __restrict__ embh) {
    int t = blockIdx.x * 256 + threadIdx.x;  // 131072 threads, one float4 each
    float4 v = ((const float4*)emb)[t];
    ushort4 h;
    h.x = f2bf(v.x); h.y = f2bf(v.y); h.z = f2bf(v.z); h.w = f2bf(v.w);
    ((ushort4*)embh)[t] = h;
}

// ---------------------------------------------------------------------------
// K0: pos_sim / conf per row (fp32 dot), zero accumulators, init min to 3.0.
// ---------------------------------------------------------------------------
__global__ __launch_bounds__(256) void k0_prep(const float* __restrict__ emb,
                        float* __restrict__ pos_sim,
                        float* __restrict__ conf,
                        float* __restrict__ pos_acc,
                        float* __restrict__ neg_acc,
                        unsigned* __restrict__ minbits) {
    int i = blockIdx.x * blockDim.x + threadIdx.x;
    int p = (i + HALF) & (B_N - 1);
    const float4* a = (const float4*)(emb + (size_t)i * D_K);
    const float4* b = (const float4*)(emb + (size_t)p * D_K);
    float acc = 0.f;
#pragma unroll
    for (int k = 0; k < D_K / 4; ++k) {
        float4 av = a[k], bv = b[k];
        acc = fmaf(av.x, bv.x, acc);
        acc = fmaf(av.y, bv.y, acc);
        acc = fmaf(av.z, bv.z, acc);
        acc = fmaf(av.w, bv.w, acc);
    }
    float ps = expf(acc * 2.0f);
    pos_sim[i] = ps;
    conf[i]    = (logf(ps) * 0.5f >= 0.8f) ? 1.0f : 0.0f;
    pos_acc[i] = 0.f;
    neg_acc[i] = 0.f;
    if (i == 0) *minbits = __float_as_uint(3.0f);
}

// ---------------------------------------------------------------------------
// K1: global min of diff_sim over the valid upper triangle (diffs >= 0, so
// uint-bit atomicMin == float min).
// ---------------------------------------------------------------------------
__global__ __launch_bounds__(256) void k1_min(const ushort* __restrict__ embh,
                                              const float* __restrict__ pos_sim,
                                              unsigned* __restrict__ minbits) {
    int bi = blockIdx.y, bj = blockIdx.x;
    if (bj < bi) return;   // lower-tri tiles contribute only 3.0 (covered by init)

    __shared__ ushort Al[BT * D_K];
    __shared__ ushort Bl[BT * D_K];
    stage_tile(embh, bi * BT, Al);
    stage_tile(embh, bj * BT, Bl);
    __syncthreads();

    int lane = threadIdx.x & 63, wid = threadIdx.x >> 6;
    int wr = wid >> 1, wc = wid & 1;
    f32x4 acc[4][4];
    tile_mfma(Al, Bl, lane, wr, wc, acc);

    float lmin = 3.0f;
    int ibase = bi * BT + wr * 64 + ((lane >> 4) << 2);
    int jbase = bj * BT + wc * 64 + (lane & 15);
#pragma unroll
    for (int m = 0; m < 4; ++m) {
#pragma unroll
        for (int reg = 0; reg < 4; ++reg) {
            int i = ibase + m * 16 + reg;
            float psi = pos_sim[i];
#pragma unroll
            for (int n = 0; n < 4; ++n) {
                int j = jbase + n * 16;
                if (j > i && !(i < HALF && j == i + HALF)) {
                    float s = sim_of(acc[m][n][reg]);
                    lmin = fminf(lmin, fabsf(s - psi));
                }
            }
        }
    }
#pragma unroll
    for (int off = 32; off; off >>= 1)
        lmin = fminf(lmin, __shfl_xor(lmin, off));
    __shared__ float wmin[4];
    if (lane == 0) wmin[wid] = lmin;
    __syncthreads();
    if (threadIdx.x == 0) {
        float bm = fminf(fminf(wmin[0], wmin[1]), fminf(wmin[2], wmin[3]));
        atomicMin(minbits, __float_as_uint(bm));
    }
}

// ---------------------------------------------------------------------------
// K2: per-row sums of new_pos / new_neg, exact per-element reference formula.
// sim recomputed bit-identically to K1 (same tile_mfma + sim_of).
// ---------------------------------------------------------------------------
__global__ __launch_bounds__(256) void k2_sum(const ushort* __restrict__ embh,
                                              const float* __restrict__ pos_sim,
                                              const float* __restrict__ conf,
                                              const unsigned* __restrict__ minbits,
                                              float* __restrict__ pos_acc,
                                              float* __restrict__ neg_acc) {
    int bi = blockIdx.y, bj = blockIdx.x;

    __shared__ ushort Al[BT * D_K];
    __shared__ ushort Bl[BT * D_K];
    stage_tile(embh, bi * BT, Al);
    stage_tile(embh, bj * BT, Bl);
    __syncthreads();

    int lane = threadIdx.x & 63, wid = threadIdx.x >> 6;
    int wr = wid >> 1, wc = wid & 1;
    f32x4 acc[4][4];
    tile_mfma(Al, Bl, lane, wr, wc, acc);

    float minv = __uint_as_float(*minbits);

    int ibase = bi * BT + wr * 64 + ((lane >> 4) << 2);
    int jbase = bj * BT + wc * 64 + (lane & 15);
#pragma unroll
    for (int m = 0; m < 4; ++m) {
#pragma unroll
        for (int reg = 0; reg < 4; ++reg) {
            int i = ibase + m * 16 + reg;
            float psi = pos_sim[i];
            bool ci = (conf[i] != 0.f);
            int pidx = (i + HALF) & (B_N - 1);
            float prow = 0.f, nrow = 0.f;
#pragma unroll
            for (int n = 0; n < 4; ++n) {
                int j = jbase + n * 16;
                float s = sim_of(acc[m][n][reg]);
                bool is_pos  = (j == pidx);
                bool is_diag = (j == i);
                float all_neg = (!is_pos && !is_diag) ? s : 0.f;
                float d = (j > i && !(i < HALF && j == i + HALF))
                              ? fabsf(s - psi) : 3.0f;
                bool sel = ci && (d == minv);
                float np = is_pos ? s : (sel ? 0.5f * all_neg : 0.f);
                float nn = (sel && all_neg != 0.f) ? 0.5f * all_neg : all_neg;
                prow += np;
                nrow += nn;
            }
            // sum over the 16 lanes (j-direction) sharing this row
#pragma unroll
            for (int off = 1; off < 16; off <<= 1) {
                prow += __shfl_xor(prow, off);
                nrow += __shfl_xor(nrow, off);
            }
            if ((lane & 15) == 0) {
                atomicAdd(&pos_acc[i], prow);
                atomicAdd(&neg_acc[i], nrow);
            }
        }
    }
}

// ---------------------------------------------------------------------------
// K3: loss = -mean(log(pos / (pos + neg)))
// ---------------------------------------------------------------------------
__global__ __launch_bounds__(1024) void k3_loss(const float* __restrict__ pos_acc,
                                                const float* __restrict__ neg_acc,
                                                float* __restrict__ out) {
    int t = threadIdx.x;
    float s = 0.f;
#pragma unroll
    for (int k = 0; k < 4; ++k) {
        int i = t + k * 1024;
        float p = pos_acc[i], q = neg_acc[i];
        s += logf(p / (p + q));
    }
#pragma unroll
    for (int off = 32; off; off >>= 1) s += __shfl_xor(s, off);
    __shared__ float red[16];
    if ((t & 63) == 0) red[t >> 6] = s;
    __syncthreads();
    if (t == 0) {
        float tot = 0.f;
#pragma unroll
        for (int w = 0; w < 16; ++w) tot += red[w];
        *out = -tot / (float)B_N;
    }
}

// ---------------------------------------------------------------------------
extern "C" void kernel_launch(void* const* d_in, const int* in_sizes, int n_in,
                              void* d_out, int out_size, void* d_ws, size_t ws_size,
                              hipStream_t stream) {
    const float* emb = (const float*)d_in[0];
    float* out = (float*)d_out;

    float* ws = (float*)d_ws;
    float*    pos_sim = ws;                      // 4096 f32
    float*    conf    = ws + 4096;               // 4096 f32
    float*    pos_acc = ws + 8192;               // 4096 f32
    float*    neg_acc = ws + 12288;              // 4096 f32
    unsigned* minbits = (unsigned*)(ws + 16384); // 1 u32
    ushort*   embh    = (ushort*)(ws + 16400);   // byte 65600, 16B-aligned; 1MB

    k_convert<<<512, 256, 0, stream>>>(emb, embh);
    k0_prep<<<16, 256, 0, stream>>>(emb, pos_sim, conf, pos_acc, neg_acc, minbits);

    dim3 grid(NBT, NBT);
    k1_min<<<grid, 256, 0, stream>>>(embh, pos_sim, minbits);
    k2_sum<<<grid, 256, 0, stream>>>(embh, pos_sim, conf, minbits, pos_acc, neg_acc);
    k3_loss<<<1, 1024, 0, stream>>>(pos_acc, neg_acc, out);
}

// Round 5
// 46.713 us; speedup vs baseline: 4.0634x; 1.4508x over previous
//
#include <hip/hip_runtime.h>
#include <math.h>

#define B_N  4096
#define HALF 2048
#define D_K  128
#define BT   128
#define NBT  32      // 4096/128

typedef __attribute__((ext_vector_type(8))) short bf16x8;
typedef __attribute__((ext_vector_type(4))) float f32x4;

// fp32 -> bf16 round-to-nearest-even (no NaN in this data)
__device__ __forceinline__ ushort f2bf(float x) {
    unsigned u = __float_as_uint(x);
    unsigned r = u + 0x7FFFu + ((u >> 16) & 1u);
    return (ushort)(r >> 16);
}

// Stage a 128x128 bf16 tile into LDS, XOR-swizzled on the 16B slot
// (byte ^= (row&7)<<4) so fragment ds_read_b128 is low-conflict (G4).
__device__ __forceinline__ void stage_tile(const ushort* __restrict__ embh,
                                           int row0, ushort* lds) {
    int t = threadIdx.x;
    const float4* src = (const float4*)(embh + (size_t)row0 * D_K);
    char* dst = (char*)lds;
#pragma unroll
    for (int it = 0; it < 8; ++it) {
        int f = t + 256 * it;        // 16B chunk index, 0..2047
        int r = f >> 4;              // row (16 chunks per 256B row)
        int c = f & 15;
        float4 v = src[f];
        int byte = (r << 8) | (((c ^ (r & 7)) & 15) << 4);
        *(float4*)(dst + byte) = v;
    }
}

__device__ __forceinline__ bf16x8 read_frag(const ushort* lds, int row, int kbyte) {
    int byte = ((row << 8) | kbyte) ^ ((row & 7) << 4);
    return *(const bf16x8*)((const char*)lds + byte);
}

// SWAPPED-operand MFMA, 4x1 wave decomposition: wave wr owns rows
// [wr*32, wr*32+32) x all 128 cols of the block tile. acc[m][n]:
//   i = bi*128 + wr*32 + m*16 + (lane&15)     (C/D col side)
//   j = bj*128 + n*16 + (lane>>4)*4 + reg     (C/D row side)
// Layouts pinned by round-2's passing kernel (A-frag row=lane&15,
// B-frag col=lane&15, k=(lane>>4)*8+e; C/D col=lane&15,row=(lane>>4)*4+reg).
__device__ __forceinline__ void tile_mfma_sw(const ushort* Al, const ushort* Bl,
                                             int lane, int wr, f32x4 acc[2][8]) {
#pragma unroll
    for (int m = 0; m < 2; ++m)
#pragma unroll
        for (int n = 0; n < 8; ++n) acc[m][n] = (f32x4){0.f, 0.f, 0.f, 0.f};

    int rA = wr * 32 + (lane & 15);
    int rB = (lane & 15);
    int kb0 = (lane >> 4) << 4;
#pragma unroll
    for (int ks = 0; ks < 4; ++ks) {
        int kb = ks * 64 + kb0;
        bf16x8 a[2], b[8];
#pragma unroll
        for (int m = 0; m < 2; ++m) a[m] = read_frag(Al, rA + m * 16, kb);
#pragma unroll
        for (int n = 0; n < 8; ++n) b[n] = read_frag(Bl, rB + n * 16, kb);
#pragma unroll
        for (int m = 0; m < 2; ++m)
#pragma unroll
            for (int n = 0; n < 8; ++n)
                acc[m][n] = __builtin_amdgcn_mfma_f32_16x16x32_bf16(
                    b[n], a[m], acc[m][n], 0, 0, 0);
    }
}

// ---------------------------------------------------------------------------
// K0: bf16 convert + pos_sim/conf per row + zero correction arrays + min init
// ---------------------------------------------------------------------------
__global__ __launch_bounds__(256) void k0_prep(const float* __restrict__ emb,
                                               ushort* __restrict__ embh,
                                               float* __restrict__ pos_sim,
                                               float* __restrict__ conf,
                                               float* __restrict__ pos_extra,
                                               float* __restrict__ neg_sub,
                                               unsigned* __restrict__ minbits) {
    int gtid = blockIdx.x * 256 + threadIdx.x;   // 0..131071
    float4 v = ((const float4*)emb)[gtid];
    ushort4 h;
    h.x = f2bf(v.x); h.y = f2bf(v.y); h.z = f2bf(v.z); h.w = f2bf(v.w);
    ((ushort4*)embh)[gtid] = h;
    if (gtid < B_N) {
        int i = gtid, p = (i + HALF) & (B_N - 1);
        const float4* a = (const float4*)(emb + (size_t)i * D_K);
        const float4* b = (const float4*)(emb + (size_t)p * D_K);
        float acc = 0.f;
#pragma unroll
        for (int k = 0; k < D_K / 4; ++k) {
            float4 av = a[k], bv = b[k];
            acc = fmaf(av.x, bv.x, acc);
            acc = fmaf(av.y, bv.y, acc);
            acc = fmaf(av.z, bv.z, acc);
            acc = fmaf(av.w, bv.w, acc);
        }
        float ps = expf(acc * 2.0f);
        pos_sim[i]   = ps;
        conf[i]      = (logf(ps) * 0.5f >= 0.8f) ? 1.0f : 0.0f;
        pos_extra[i] = 0.f;
        neg_sub[i]   = 0.f;
        if (i == 0) *minbits = __float_as_uint(3.0f);
    }
}

// ---------------------------------------------------------------------------
// K1: single GEMM pass. Per block (bi,bj): sim tile, row neg-partials
// (each row's full 128-col partial produced by exactly ONE wave -> one
// non-colliding store per slot), block-min of diff, global atomicMin.
// ---------------------------------------------------------------------------
__global__ __launch_bounds__(256, 2) void k1_main(const ushort* __restrict__ embh,
                                                  const float* __restrict__ pos_sim,
                                                  float* __restrict__ negpart,
                                                  unsigned* __restrict__ block_min,
                                                  unsigned* __restrict__ minbits) {
    int bi = blockIdx.y, bj = blockIdx.x;
    __shared__ ushort Al[BT * D_K];
    __shared__ ushort Bl[BT * D_K];
    stage_tile(embh, bi * BT, Al);
    stage_tile(embh, bj * BT, Bl);
    __syncthreads();

    int tid = threadIdx.x, lane = tid & 63, wr = tid >> 6;
    f32x4 acc[2][8];
    tile_mfma_sw(Al, Bl, lane, wr, acc);

    int ib = bi * BT + wr * 32 + (lane & 15);
    int jb = bj * BT + ((lane >> 4) << 2);
    bool upper = (bj >= bi);
    float lmin = 3.0f;
#pragma unroll
    for (int m = 0; m < 2; ++m) {
        int i = ib + m * 16;
        float psi = pos_sim[i];
        int pidx = (i + HALF) & (B_N - 1);
        float negp = 0.f;
#pragma unroll
        for (int n = 0; n < 8; ++n)
#pragma unroll
            for (int reg = 0; reg < 4; ++reg) {
                float s = __expf(acc[m][n][reg] * 2.0f);
                int j = jb + n * 16 + reg;
                if (j != i && j != pidx) negp += s;
                if (upper && j > i && !(i < HALF && j == i + HALF))
                    lmin = fminf(lmin, fabsf(s - psi));
            }
        negp += __shfl_xor(negp, 16);
        negp += __shfl_xor(negp, 32);
        if (lane < 16) negpart[bj * B_N + i] = negp;   // unique slot per (i,bj)
    }
#pragma unroll
    for (int off = 32; off; off >>= 1)
        lmin = fminf(lmin, __shfl_xor(lmin, off));
    __shared__ float wred[4];
    if (lane == 0) wred[wr] = lmin;
    __syncthreads();
    if (tid == 0) {
        float bm = fminf(fminf(wred[0], wred[1]), fminf(wred[2], wred[3]));
        block_min[bi * NBT + bj] = __float_as_uint(bm);
        atomicMin(minbits, __float_as_uint(bm));
    }
}

// ---------------------------------------------------------------------------
// K2: rescan ONLY blocks whose block_min equals the global min (bit-identical
// recompute => exact equality test). Applies the false-negative corrections:
// at sel & j not in {i,pidx}: pos += CW*sim, neg -= CW*sim.
// ---------------------------------------------------------------------------
__global__ __launch_bounds__(256, 2) void k2_rescan(const ushort* __restrict__ embh,
                                                    const float* __restrict__ pos_sim,
                                                    const float* __restrict__ conf,
                                                    const unsigned* __restrict__ block_min,
                                                    const unsigned* __restrict__ minbits,
                                                    float* __restrict__ pos_extra,
                                                    float* __restrict__ neg_sub) {
    int bi = blockIdx.y, bj = blockIdx.x;
    unsigned minv_b = *minbits;
    if (block_min[bi * NBT + bj] != minv_b) return;   // uniform exit (typical path)

    __shared__ ushort Al[BT * D_K];
    __shared__ ushort Bl[BT * D_K];
    stage_tile(embh, bi * BT, Al);
    stage_tile(embh, bj * BT, Bl);
    __syncthreads();

    int tid = threadIdx.x, lane = tid & 63, wr = tid >> 6;
    f32x4 acc[2][8];
    tile_mfma_sw(Al, Bl, lane, wr, acc);

    int ib = bi * BT + wr * 32 + (lane & 15);
    int jb = bj * BT + ((lane >> 4) << 2);
#pragma unroll
    for (int m = 0; m < 2; ++m) {
        int i = ib + m * 16;
        float psi = pos_sim[i];
        bool ci = (conf[i] != 0.f);
        int pidx = (i + HALF) & (B_N - 1);
#pragma unroll
        for (int n = 0; n < 8; ++n)
#pragma unroll
            for (int reg = 0; reg < 4; ++reg) {
                float s = __expf(acc[m][n][reg] * 2.0f);
                int j = jb + n * 16 + reg;
                float d = (j > i && !(i < HALF && j == i + HALF))
                              ? fabsf(s - psi) : 3.0f;
                if (ci && __float_as_uint(d) == minv_b && j != i && j != pidx) {
                    atomicAdd(&pos_extra[i], 0.5f * s);
                    atomicAdd(&neg_sub[i],   0.5f * s);
                }
            }
    }
}

// ---------------------------------------------------------------------------
// K3: per-row totals from negpart + corrections, then the loss.
// Single block => deterministic reduction.
// ---------------------------------------------------------------------------
__global__ __launch_bounds__(1024) void k3_loss(const float* __restrict__ pos_sim,
                                                const float* __restrict__ pos_extra,
                                                const float* __restrict__ neg_sub,
                                                const float* __restrict__ negpart,
                                                float* __restrict__ out) {
    int t = threadIdx.x;
    float s = 0.f;
#pragma unroll
    for (int k = 0; k < 4; ++k) {
        int i = t + k * 1024;
        float nb = 0.f;
#pragma unroll
        for (int p = 0; p < NBT; ++p) nb += negpart[p * B_N + i];
        float pos = pos_sim[i] + pos_extra[i];
        float neg = nb - neg_sub[i];
        s += logf(pos / (pos + neg));
    }
#pragma unroll
    for (int off = 32; off; off >>= 1) s += __shfl_xor(s, off);
    __shared__ float red[16];
    if ((t & 63) == 0) red[t >> 6] = s;
    __syncthreads();
    if (t == 0) {
        float tot = 0.f;
#pragma unroll
        for (int w = 0; w < 16; ++w) tot += red[w];
        *out = -tot / (float)B_N;
    }
}

// ---------------------------------------------------------------------------
extern "C" void kernel_launch(void* const* d_in, const int* in_sizes, int n_in,
                              void* d_out, int out_size, void* d_ws, size_t ws_size,
                              hipStream_t stream) {
    const float* emb = (const float*)d_in[0];
    float* out = (float*)d_out;

    char* ws = (char*)d_ws;
    ushort*   embh      = (ushort*)ws;                        // 1 MB
    float*    fbase     = (float*)(ws + 1048576);
    float*    pos_sim   = fbase;                              // 4096
    float*    conf      = fbase + 4096;                       // 4096
    float*    pos_extra = fbase + 8192;                       // 4096
    float*    neg_sub   = fbase + 12288;                      // 4096
    float*    negpart   = fbase + 16384;                      // 32*4096
    unsigned* block_min = (unsigned*)(fbase + 16384 + NBT * B_N);  // 1024
    unsigned* minbits   = block_min + 1024;                   // 1

    k0_prep<<<512, 256, 0, stream>>>(emb, embh, pos_sim, conf,
                                     pos_extra, neg_sub, minbits);
    dim3 grid(NBT, NBT);
    k1_main<<<grid, 256, 0, stream>>>(embh, pos_sim, negpart, block_min, minbits);
    k2_rescan<<<grid, 256, 0, stream>>>(embh, pos_sim, conf, block_min, minbits,
                                        pos_extra, neg_sub);
    k3_loss<<<1, 1024, 0, stream>>>(pos_sim, pos_extra, neg_sub, negpart, out);
}

// Round 6
// 38.972 us; speedup vs baseline: 4.8706x; 1.1986x over previous
//
#include <hip/hip_runtime.h>
#include <hip/hip_bf16.h>
#include <math.h>

#define B_N  4096
#define HALF 2048
#define D_K  128
#define BT   128
#define NBT  32      // 4096/128

typedef __attribute__((ext_vector_type(8))) short bf16x8;
typedef __attribute__((ext_vector_type(4))) float f32x4;

// ---------------------------------------------------------------------------
// Stage a 128x128 fp32 tile -> bf16 LDS (convert in flight, packed cvt_pk),
// XOR-swizzled on the 16B slot (byte ^= (row&7)<<4) for conflict-free
// fragment ds_read_b128 (G4).
// ---------------------------------------------------------------------------
__device__ __forceinline__ void stage_tile_cvt(const float* __restrict__ emb,
                                               int row0, ushort* lds) {
    int t = threadIdx.x;
    const float4* src = (const float4*)(emb + (size_t)row0 * D_K);
    char* dst = (char*)lds;
#pragma unroll
    for (int it = 0; it < 8; ++it) {
        int f = t + 256 * it;        // 16B dst chunk index, 0..2047
        int r = f >> 4;              // row 0..127 (16 chunks per 256B bf16 row)
        int c = f & 15;              // chunk within row (8 bf16 each)
        float4 v0 = src[r * 32 + c * 2];
        float4 v1 = src[r * 32 + c * 2 + 1];
        union { __hip_bfloat162 h; unsigned u; } c0, c1, c2, c3;
        c0.h = __float22bfloat162_rn(make_float2(v0.x, v0.y));
        c1.h = __float22bfloat162_rn(make_float2(v0.z, v0.w));
        c2.h = __float22bfloat162_rn(make_float2(v1.x, v1.y));
        c3.h = __float22bfloat162_rn(make_float2(v1.z, v1.w));
        uint4 w = {c0.u, c1.u, c2.u, c3.u};
        int byte = (r << 8) | (((c ^ (r & 7)) & 15) << 4);
        *(uint4*)(dst + byte) = w;
    }
}

__device__ __forceinline__ bf16x8 read_frag(const ushort* lds, int row, int kbyte) {
    int byte = ((row << 8) | kbyte) ^ ((row & 7) << 4);
    return *(const bf16x8*)((const char*)lds + byte);
}

// SWAPPED-operand MFMA, 4x1 wave decomposition (wave wr owns rows
// [wr*32, wr*32+32) x all 128 cols). Layouts pinned by round-2/5 passes:
//   i = bi*128 + wr*32 + m*16 + (lane&15)
//   j = bj*128 + n*16 + (lane>>4)*4 + reg
__device__ __forceinline__ void tile_mfma_sw(const ushort* Al, const ushort* Bl,
                                             int lane, int wr, f32x4 acc[2][8]) {
#pragma unroll
    for (int m = 0; m < 2; ++m)
#pragma unroll
        for (int n = 0; n < 8; ++n) acc[m][n] = (f32x4){0.f, 0.f, 0.f, 0.f};

    int rA = wr * 32 + (lane & 15);
    int rB = (lane & 15);
    int kb0 = (lane >> 4) << 4;
#pragma unroll
    for (int ks = 0; ks < 4; ++ks) {
        int kb = ks * 64 + kb0;
        bf16x8 a[2], b[8];
#pragma unroll
        for (int m = 0; m < 2; ++m) a[m] = read_frag(Al, rA + m * 16, kb);
#pragma unroll
        for (int n = 0; n < 8; ++n) b[n] = read_frag(Bl, rB + n * 16, kb);
#pragma unroll
        for (int m = 0; m < 2; ++m)
#pragma unroll
            for (int n = 0; n < 8; ++n)
                acc[m][n] = __builtin_amdgcn_mfma_f32_16x16x32_bf16(
                    b[n], a[m], acc[m][n], 0, 0, 0);
    }
}

// ---------------------------------------------------------------------------
// K0 (tiny): pos_sim / conf per row (fp32 dot) + counters init.
// ---------------------------------------------------------------------------
__global__ __launch_bounds__(256) void k0_prep(const float* __restrict__ emb,
                                               float* __restrict__ pos_sim,
                                               float* __restrict__ conf,
                                               unsigned* __restrict__ minbits,
                                               unsigned* __restrict__ counter) {
    int i = blockIdx.x * 256 + threadIdx.x;      // 4096 threads
    int p = i ^ HALF;
    const float4* a = (const float4*)(emb + (size_t)i * D_K);
    const float4* b = (const float4*)(emb + (size_t)p * D_K);
    float acc = 0.f;
#pragma unroll
    for (int k = 0; k < D_K / 4; ++k) {
        float4 av = a[k], bv = b[k];
        acc = fmaf(av.x, bv.x, acc);
        acc = fmaf(av.y, bv.y, acc);
        acc = fmaf(av.z, bv.z, acc);
        acc = fmaf(av.w, bv.w, acc);
    }
    float ps = expf(acc * 2.0f);
    pos_sim[i] = ps;
    conf[i]    = (logf(ps) * 0.5f >= 0.8f) ? 1.0f : 0.0f;
    if (i == 0) { *minbits = __float_as_uint(3.0f); *counter = 0u; }
}

// ---------------------------------------------------------------------------
// K1: the only GEMM pass. Per block (bi,bj): sim tile (bf16 MFMA), row
// neg-partials, block-min of diff, and speculative correction partials
// (elements with diff == block_min; only meaningful if this block's min
// turns out to be the global min — k3 filters). Epilogue specialized on
// block-uniform category: diag (bi==bj), pos-tile (bj==bi^16), other.
// ---------------------------------------------------------------------------
__global__ __launch_bounds__(256, 2) void k1_main(const float* __restrict__ emb,
                                                  const float* __restrict__ pos_sim,
                                                  const float* __restrict__ conf,
                                                  float* __restrict__ negpart,
                                                  float* __restrict__ corrpart,
                                                  unsigned* __restrict__ block_min,
                                                  unsigned* __restrict__ minbits) {
    int bi = blockIdx.y, bj = blockIdx.x;
    __shared__ ushort Al[BT * D_K];
    __shared__ ushort Bl[BT * D_K];
    stage_tile_cvt(emb, bi * BT, Al);
    stage_tile_cvt(emb, bj * BT, Bl);
    __syncthreads();

    int tid = threadIdx.x, lane = tid & 63, wr = tid >> 6;
    f32x4 acc[2][8];
    tile_mfma_sw(Al, Bl, lane, wr, acc);

    // exp in place: acc now holds sim values
#pragma unroll
    for (int m = 0; m < 2; ++m)
#pragma unroll
        for (int n = 0; n < 8; ++n)
#pragma unroll
            for (int reg = 0; reg < 4; ++reg)
                acc[m][n][reg] = __expf(acc[m][n][reg] * 2.0f);

    int ib = bi * BT + wr * 32 + (lane & 15);
    int jb = bj * BT + ((lane >> 4) << 2);
    bool diag = (bi == bj), post = (bj == (bi ^ 16)), up = (bj > bi);

    float lmin = 3.0f;
    float psi_[2];
#pragma unroll
    for (int m = 0; m < 2; ++m) {
        int i = ib + m * 16;
        float psi = pos_sim[i];
        psi_[m] = psi;
        int pidx = i ^ HALF;
        float negp = 0.f;
        if (!diag && !post) {
            // no exclusions; j>i automatic iff up
#pragma unroll
            for (int n = 0; n < 8; ++n)
#pragma unroll
                for (int reg = 0; reg < 4; ++reg) {
                    float s = acc[m][n][reg];
                    negp += s;
                    if (up) lmin = fminf(lmin, fabsf(s - psi));
                }
        } else if (diag) {
#pragma unroll
            for (int n = 0; n < 8; ++n)
#pragma unroll
                for (int reg = 0; reg < 4; ++reg) {
                    float s = acc[m][n][reg];
                    int j = jb + n * 16 + reg;
                    if (j != i) negp += s;
                    if (j > i) lmin = fminf(lmin, fabsf(s - psi));
                }
        } else {  // pos-tile
#pragma unroll
            for (int n = 0; n < 8; ++n)
#pragma unroll
                for (int reg = 0; reg < 4; ++reg) {
                    float s = acc[m][n][reg];
                    int j = jb + n * 16 + reg;
                    if (j != pidx) {
                        negp += s;
                        if (up) lmin = fminf(lmin, fabsf(s - psi));
                    }
                }
        }
        negp += __shfl_xor(negp, 16);
        negp += __shfl_xor(negp, 32);
        if (lane < 16) negpart[bj * B_N + i] = negp;   // unique slot per (i,bj)
    }

    // block min of diff
#pragma unroll
    for (int off = 32; off; off >>= 1)
        lmin = fminf(lmin, __shfl_xor(lmin, off));
    __shared__ float wred[4];
    if (lane == 0) wred[wr] = lmin;
    __syncthreads();
    float bmin = fminf(fminf(wred[0], wred[1]), fminf(wred[2], wred[3]));
    if (tid == 0) {
        block_min[bi * NBT + bj] = __float_as_uint(bmin);
        atomicMin(minbits, __float_as_uint(bmin));
    }

    // speculative correction partials (wave-uniform skip when no conf row)
    float corr_[2] = {0.f, 0.f};
    bool anyc = (conf[ib] != 0.f) || (conf[ib + 16] != 0.f);
    if (__any(anyc)) {
#pragma unroll
        for (int m = 0; m < 2; ++m) {
            int i = ib + m * 16;
            float psi = psi_[m];
            int pidx = i ^ HALF;
            bool ci = (conf[i] != 0.f);
            float corr = 0.f;
#pragma unroll
            for (int n = 0; n < 8; ++n)
#pragma unroll
                for (int reg = 0; reg < 4; ++reg) {
                    float s = acc[m][n][reg];
                    int j = jb + n * 16 + reg;
                    bool valid = (j > i) && !(j == pidx && i < HALF);
                    float d = valid ? fabsf(s - psi) : 3.0f;
                    if (ci && d == bmin && j != i && j != pidx)
                        corr += 0.5f * s;
                }
            corr += __shfl_xor(corr, 16);
            corr += __shfl_xor(corr, 32);
            corr_[m] = corr;
        }
    }
    if (lane < 16) {
        corrpart[bj * B_N + ib]      = corr_[0];
        corrpart[bj * B_N + ib + 16] = corr_[1];
    }
}

// ---------------------------------------------------------------------------
// K3: 32 blocks (one per 128-row tile). Per row: neg = sum of negpart,
// corr = sum of corrpart over blocks whose min equals the global min.
// Block partial -> last-block finalize (device atomics, fixed-order sums).
// ---------------------------------------------------------------------------
__global__ __launch_bounds__(128) void k3_loss(const float* __restrict__ pos_sim,
                                               const float* __restrict__ negpart,
                                               const float* __restrict__ corrpart,
                                               const unsigned* __restrict__ block_min,
                                               const unsigned* __restrict__ minbits,
                                               float* __restrict__ partial,
                                               unsigned* __restrict__ counter,
                                               float* __restrict__ out) {
    int bi = blockIdx.x, t = threadIdx.x;
    int i = bi * 128 + t;
    unsigned gm = *minbits;
    float neg = 0.f, corr = 0.f;
#pragma unroll
    for (int bj = 0; bj < NBT; ++bj) {
        neg += negpart[bj * B_N + i];
        if (block_min[bi * NBT + bj] == gm)     // block-uniform condition
            corr += corrpart[bj * B_N + i];
    }
    float pos = pos_sim[i] + corr;
    float ng  = neg - corr;
    float l = logf(pos / (pos + ng));
#pragma unroll
    for (int off = 32; off; off >>= 1) l += __shfl_xor(l, off);
    __shared__ float w2[2];
    if ((t & 63) == 0) w2[t >> 6] = l;
    __syncthreads();
    if (t == 0) {
        partial[bi] = w2[0] + w2[1];
        __threadfence();
        unsigned c = atomicAdd(counter, 1u);
        if (c == NBT - 1) {                     // last block finalizes
            __threadfence();
            float tot = 0.f;
            volatile float* vp = partial;
            for (int b = 0; b < NBT; ++b) tot += vp[b];
            *out = -tot / (float)B_N;
        }
    }
}

// ---------------------------------------------------------------------------
extern "C" void kernel_launch(void* const* d_in, const int* in_sizes, int n_in,
                              void* d_out, int out_size, void* d_ws, size_t ws_size,
                              hipStream_t stream) {
    const float* emb = (const float*)d_in[0];
    float* out = (float*)d_out;

    float* fbase = (float*)d_ws;
    float*    pos_sim   = fbase;                        // 4096
    float*    conf      = fbase + 4096;                 // 4096
    float*    negpart   = fbase + 8192;                 // 32*4096 = 131072
    float*    corrpart  = negpart + NBT * B_N;          // 131072
    float*    partial   = corrpart + NBT * B_N;         // 32
    unsigned* block_min = (unsigned*)(partial + 32);    // 1024
    unsigned* minbits   = block_min + 1024;             // 1
    unsigned* counter   = minbits + 1;                  // 1

    k0_prep<<<16, 256, 0, stream>>>(emb, pos_sim, conf, minbits, counter);
    dim3 grid(NBT, NBT);
    k1_main<<<grid, 256, 0, stream>>>(emb, pos_sim, conf, negpart, corrpart,
                                      block_min, minbits);
    k3_loss<<<NBT, 128, 0, stream>>>(pos_sim, negpart, corrpart, block_min,
                                     minbits, partial, counter, out);
}